// Round 4
// baseline (9476.270 us; speedup 1.0000x reference)
//
#include <hip/hip_runtime.h>
#include <hip/hip_fp16.h>

#define BATCH 32
#define SEQ   1024
#define DIM   512

typedef _Float16 f16x2 __attribute__((ext_vector_type(2)));
typedef _Float16 f16x8 __attribute__((ext_vector_type(8)));
typedef float    f32x4 __attribute__((ext_vector_type(4)));
typedef unsigned int u32x4 __attribute__((ext_vector_type(4)));

union U4H8 { u32x4 u; f16x8 h8; };
union UU4 { uint4 s; u32x4 v; };

static __device__ __forceinline__ f16x2 as_f16x2(unsigned int v) {
    union { unsigned int u; f16x2 h; } x; x.u = v; return x.h;
}

static __device__ __forceinline__ float fdot2(unsigned int a, unsigned int b, float c) {
    return __builtin_amdgcn_fdot2(as_f16x2(a), as_f16x2(b), c, false);
}

static __device__ __forceinline__ unsigned pack2h(float a, float b) {
    auto p = __builtin_amdgcn_cvt_pkrtz(a, b);
    union { decltype(p) h; unsigned u; } x; x.h = p; return x.u;
}

static __device__ __forceinline__ float tanh_fast(float x) {
    float e = __expf(2.0f * x);
    return 1.0f - 2.0f / (e + 1.0f);
}

// ---------------------------------------------------------------------------
// Pack W_xh into MFMA B-fragment layout (fp16) for gemm_xw.
// ---------------------------------------------------------------------------
__global__ void pack_wxh(const float* __restrict__ Wxh, __half* __restrict__ WpXh) {
    int id = blockIdx.x * blockDim.x + threadIdx.x;   // 0 .. 262143
    int n = id & 511;
    int k = id >> 9;
    WpXh[((k >> 5) * 512 + n) * 32 + ((k >> 3) & 3) * 8 + (k & 7)] = __float2half(Wxh[k * 512 + n]);
}

// ---------------------------------------------------------------------------
// Pack W_hh cols 0..255 (the VALU half) as half2 k-pair words.
//  word(w,t) = {Whh[2w][t], Whh[2w+1][t]}; w in [0,256), t = col in [0,256).
//  w <  160 -> WvA[w*256 + t]                 (VGPR-resident at runtime)
//  w >= 160 -> WvB[((w-160)>>2)*256 + t][ (w-160)&3 ]   (LDS-resident uint4)
// ---------------------------------------------------------------------------
__global__ void pack_whh_valu(const float* __restrict__ Whh,
                              unsigned* __restrict__ WvA,
                              unsigned* __restrict__ WvB) {
    int id = blockIdx.x * blockDim.x + threadIdx.x;   // 0 .. 65535
    int w = id >> 8;
    int t = id & 255;
    unsigned word = pack2h(Whh[(2 * w) * 512 + t], Whh[(2 * w + 1) * 512 + t]);
    if (w < 160) WvA[w * 256 + t] = word;
    else {
        int ww = w - 160;
        WvB[((ww >> 2) * 256 + t) * 4 + (ww & 3)] = word;
    }
}

// ---------------------------------------------------------------------------
// Pack W_hh cols 256..511 (the MFMA half) into 16x16x32 B-fragment layout.
// ---------------------------------------------------------------------------
__global__ void pack_whh_mfma(const float* __restrict__ Whh, __half* __restrict__ WpH) {
    int id = blockIdx.x * blockDim.x + threadIdx.x;   // 0 .. 131071
    int n2 = id & 255;         // col - 256
    int k  = id >> 8;          // 0..511
    WpH[((k >> 5) * 256 + n2) * 32 + ((k >> 3) & 3) * 8 + (k & 7)] =
        __float2half(Whh[k * 512 + 256 + n2]);
}

// ---------------------------------------------------------------------------
// Kernel 1: xw = x @ W_xh + b (fp16 MFMA 16x16x32, fp32 out). Unchanged.
// ---------------------------------------------------------------------------
__global__ __launch_bounds__(256) void gemm_xw(const float* __restrict__ X,
                                               const __half* __restrict__ Wp,
                                               const float* __restrict__ bias,
                                               float* __restrict__ out) {
    const int nb   = blockIdx.x;
    const int mb   = blockIdx.y;
    const int lane = threadIdx.x & 63;
    const int wave = threadIdx.x >> 6;
    const int q    = lane >> 4;
    const int r16  = lane & 15;
    const int row  = mb * 64 + wave * 16 + r16;

    const float4* Xf4  = (const float4*)X;
    const uint4*  WpU4 = (const uint4*)Wp;

    f32x4 acc[4];
    #pragma unroll
    for (int nt = 0; nt < 4; ++nt) acc[nt] = (f32x4){0.f, 0.f, 0.f, 0.f};

    #pragma unroll 4
    for (int kb = 0; kb < 16; ++kb) {
        float4 a0 = Xf4[row * 128 + kb * 8 + q * 2];
        float4 a1 = Xf4[row * 128 + kb * 8 + q * 2 + 1];
        f16x8 af;
        af[0] = (_Float16)a0.x; af[1] = (_Float16)a0.y;
        af[2] = (_Float16)a0.z; af[3] = (_Float16)a0.w;
        af[4] = (_Float16)a1.x; af[5] = (_Float16)a1.y;
        af[6] = (_Float16)a1.z; af[7] = (_Float16)a1.w;
        #pragma unroll
        for (int nt = 0; nt < 4; ++nt) {
            int col = nb * 64 + nt * 16 + r16;
            U4H8 bf; UU4 tmp; tmp.s = WpU4[(kb * 512 + col) * 4 + q];
            bf.u = tmp.v;
            acc[nt] = __builtin_amdgcn_mfma_f32_16x16x32_f16(af, bf.h8, acc[nt], 0, 0, 0);
        }
    }

    const int rbase = mb * 64 + wave * 16 + q * 4;
    #pragma unroll
    for (int nt = 0; nt < 4; ++nt) {
        int col = nb * 64 + nt * 16 + r16;
        float bv = bias[col];
        #pragma unroll
        for (int rr = 0; rr < 4; ++rr) {
            out[(size_t)(rbase + rr) * 512 + col] = acc[nt][rr] + bv;
        }
    }
}

// ---------------------------------------------------------------------------
// Kernel 2: recurrence. 32 blocks x 256 thr (4 waves, 1 wave/SIMD).
// Cols 0..255 on VALU (fdot2 + readlane-h): W words 0..159 in VGPR (<=256-v
// cap!), words 160..255 in LDS. Cols 256..511 on the MFMA pipe: B-frags =
// 256 AGPRs/lane pinned with "+a"; A = h replicated over all 16 rows; row 0
// of D is the matvec. 4 MFMA : 32 VALU interleave keeps both pipes fed from
// the single wave per SIMD.
// ---------------------------------------------------------------------------
#define H_WORD(w) __builtin_amdgcn_readlane((int)((((w) & 3) == 0) ? hva : (((w) & 3) == 1) ? hvb : (((w) & 3) == 2) ? hvc : hvd), (w) >> 2)

__global__ __launch_bounds__(256, 1) void rnn_rec(const unsigned* __restrict__ WvA,
                                                  const u32x4* __restrict__ WvB,
                                                  const u32x4* __restrict__ WpH,
                                                  float* __restrict__ out) {
    extern __shared__ char smem[];
    u32x4*  LW   = (u32x4*)smem;               // 24*256*16 = 96 KB
    __half* hlds = (__half*)(smem + 98304);    // 1 KB: h as fp16[512]
    float*  pre  = (float*)(smem + 99328);     // 1 KB: MFMA pre-activations

    const int b    = blockIdx.x;
    const int t    = threadIdx.x;
    const int lane = t & 63;
    const int wave = t >> 6;
    const int q    = lane >> 4;    // 0..3
    const int r16  = lane & 15;

    // Stage LDS-resident W (coalesced).
    #pragma unroll
    for (int i = 0; i < 24; ++i) LW[i * 256 + t] = WvB[i * 256 + t];

    // VGPR-resident VALU W: words 0..159 of col t. 160 pins fits v0..v255.
    unsigned Wv[160];
    #pragma unroll
    for (int w = 0; w < 160; ++w) {
        Wv[w] = WvA[w * 256 + t];
        asm volatile("" : "+v"(Wv[w]));
    }

    // AGPR-resident MFMA B-frags: wave owns cols 256+64*wave .. +63.
    u32x4 Bf[64];
    #pragma unroll
    for (int kb = 0; kb < 16; ++kb) {
        #pragma unroll
        for (int nt = 0; nt < 4; ++nt) {
            int ncol = wave * 64 + nt * 16 + r16;
            Bf[kb * 4 + nt] = WpH[(kb * 256 + ncol) * 4 + q];
            asm volatile("" : "+a"(Bf[kb * 4 + nt]));
        }
    }

    float* orow = out + (size_t)b * SEQ * DIM;

    // Step 0: h = tanh(xw).
    float xwV = orow[t];
    float xwM = orow[256 + t];
    float hV = tanh_fast(xwV);
    float hM = tanh_fast(xwM);
    orow[t] = hV; orow[256 + t] = hM;
    hlds[t] = __float2half(hV); hlds[256 + t] = __float2half(hM);
    __syncthreads();
    u32x4 hv4 = ((const u32x4*)hlds)[lane];
    unsigned hva = hv4[0], hvb = hv4[1], hvc = hv4[2], hvd = hv4[3];
    xwV = orow[DIM + t];
    xwM = orow[DIM + 256 + t];

    #pragma unroll 1
    for (int step = 1; step < SEQ; ++step) {
        orow += DIM;
        f32x4 m[8];
        #pragma unroll
        for (int i = 0; i < 8; ++i) m[i] = (f32x4){0.f, 0.f, 0.f, 0.f};
        float a0 = 0.f, a1 = 0.f, a2 = 0.f, a3 = 0.f;

        #pragma unroll
        for (int kb = 0; kb < 16; ++kb) {
            // A-frag: h[kb*32 + q*8 .. +7], replicated over all 16 M-rows.
            f16x8 af = *(const f16x8*)(hlds + kb * 32 + q * 8);
            #pragma unroll
            for (int nt = 0; nt < 4; ++nt) {
                int c = (kb & 1) * 4 + nt;
                m[c] = __builtin_amdgcn_mfma_f32_16x16x32_f16(
                    af, __builtin_bit_cast(f16x8, Bf[kb * 4 + nt]), m[c], 0, 0, 0);
            }
            // 16 VALU k-words interleaved with the 4 MFMAs above.
            if (kb < 10) {
                #pragma unroll
                for (int j = 0; j < 16; ++j) {
                    int w = kb * 16 + j;
                    float& ac = (j & 3) == 0 ? a0 : (j & 3) == 1 ? a1 : (j & 3) == 2 ? a2 : a3;
                    ac = fdot2(Wv[w], (unsigned)H_WORD(w), ac);
                }
            } else {
                #pragma unroll
                for (int ii = 0; ii < 4; ++ii) {
                    int i = (kb - 10) * 4 + ii;      // 0..23
                    u32x4 wv = LW[i * 256 + t];
                    int w0 = 160 + i * 4;
                    a0 = fdot2(wv[0], (unsigned)H_WORD(w0 + 0), a0);
                    a1 = fdot2(wv[1], (unsigned)H_WORD(w0 + 1), a1);
                    a2 = fdot2(wv[2], (unsigned)H_WORD(w0 + 2), a2);
                    a3 = fdot2(wv[3], (unsigned)H_WORD(w0 + 3), a3);
                }
            }
        }

        float pV = xwV + ((a0 + a1) + (a2 + a3));
        hV = tanh_fast(pV);

        // MFMA row 0 -> preact buffer (lanes 0..15 hold row 0, col=r16).
        float r0 = m[0][0] + m[4][0];
        float r1 = m[1][0] + m[5][0];
        float r2 = m[2][0] + m[6][0];
        float r3 = m[3][0] + m[7][0];
        if (q == 0) {
            pre[wave * 64 +  0 + r16] = r0;
            pre[wave * 64 + 16 + r16] = r1;
            pre[wave * 64 + 32 + r16] = r2;
            pre[wave * 64 + 48 + r16] = r3;
        }
        __syncthreads();

        float pM = pre[t] + xwM;
        hM = tanh_fast(pM);

        orow[t] = hV;
        orow[256 + t] = hM;
        hlds[t] = __float2half(hV);
        hlds[256 + t] = __float2half(hM);
        __syncthreads();

        u32x4 nh = ((const u32x4*)hlds)[lane];
        hva = nh[0]; hvb = nh[1]; hvc = nh[2]; hvd = nh[3];
        // Prefetch next xw (last step reads past row 1023 but stays inside
        // the output allocation; value unused).
        xwV = orow[DIM + t];
        xwM = orow[DIM + 256 + t];
    }

    float* hf = out + (size_t)BATCH * SEQ * DIM + (size_t)b * DIM;
    hf[t] = hV;
    hf[256 + t] = hM;
}

extern "C" void kernel_launch(void* const* d_in, const int* in_sizes, int n_in,
                              void* d_out, int out_size, void* d_ws, size_t ws_size,
                              hipStream_t stream) {
    const float* X    = (const float*)d_in[0];   // [32,1024,512] fp32
    const float* Wxh  = (const float*)d_in[1];   // [512,512] fp32
    const float* Whh  = (const float*)d_in[2];   // [512,512] fp32
    const float* bias = (const float*)d_in[3];   // [512] fp32
    float* out = (float*)d_out;

    __half*   WpXh = (__half*)d_ws;                               // 512 KB @ 0
    __half*   WpH  = (__half*)((char*)d_ws + (512u << 10));       // 256 KB @ 512K
    unsigned* WvA  = (unsigned*)((char*)d_ws + (768u << 10));     // 160 KB @ 768K
    unsigned* WvB  = (unsigned*)((char*)d_ws + (928u << 10));     //  96 KB @ 928K

    (void)hipFuncSetAttribute((const void*)rnn_rec,
                              hipFuncAttributeMaxDynamicSharedMemorySize, 100352);

    pack_wxh<<<512, 512, 0, stream>>>(Wxh, WpXh);
    pack_whh_valu<<<256, 256, 0, stream>>>(Whh, WvA, WvB);
    pack_whh_mfma<<<512, 256, 0, stream>>>(Whh, WpH);
    gemm_xw<<<dim3(8, 512), 256, 0, stream>>>(X, WpXh, bias, out);
    rnn_rec<<<BATCH, 256, 100352, stream>>>(WvA, (const u32x4*)WvB, (const u32x4*)WpH, out);
}

// Round 5
// 2133.931 us; speedup vs baseline: 4.4408x; 4.4408x over previous
//
#include <hip/hip_runtime.h>
#include <hip/hip_fp16.h>

#define BATCH 32
#define SEQ   1024
#define DIM   512

typedef _Float16 f16x8 __attribute__((ext_vector_type(8)));
typedef float    f32x4 __attribute__((ext_vector_type(4)));
typedef unsigned int u32x4 __attribute__((ext_vector_type(4)));

union UU4 { uint4 s; u32x4 v; };

static __device__ __forceinline__ float tanh_fast(float x) {
    float e = __expf(2.0f * x);
    return 1.0f - 2.0f / (e + 1.0f);
}

// ---------------------------------------------------------------------------
// Pack a 512x512 fp32 row-major W into fp16 MFMA B-fragment layout:
//   Wp[((k>>5)*512 + n)*32 + ((k>>3)&3)*8 + (k&7)] = W[k][n]
// One uint4 per (k-block, col, quad) = the 16x16x32 B fragment, coalesced.
// Used for both W_xh (gemm) and W_hh (recurrence).
// ---------------------------------------------------------------------------
__global__ void pack_w(const float* __restrict__ W, __half* __restrict__ Wp) {
    int id = blockIdx.x * blockDim.x + threadIdx.x;   // 0 .. 262143
    int n = id & 511;
    int k = id >> 9;
    Wp[((k >> 5) * 512 + n) * 32 + ((k >> 3) & 3) * 8 + (k & 7)] = __float2half(W[k * 512 + n]);
}

// ---------------------------------------------------------------------------
// Kernel 1: xw = x @ W_xh + b (fp16 MFMA 16x16x32, fp32 out).
// ---------------------------------------------------------------------------
__global__ __launch_bounds__(256) void gemm_xw(const float* __restrict__ X,
                                               const __half* __restrict__ Wp,
                                               const float* __restrict__ bias,
                                               float* __restrict__ out) {
    const int nb   = blockIdx.x;
    const int mb   = blockIdx.y;
    const int lane = threadIdx.x & 63;
    const int wave = threadIdx.x >> 6;
    const int q    = lane >> 4;
    const int r16  = lane & 15;
    const int row  = mb * 64 + wave * 16 + r16;

    const float4* Xf4  = (const float4*)X;
    const uint4*  WpU4 = (const uint4*)Wp;

    f32x4 acc[4];
    #pragma unroll
    for (int nt = 0; nt < 4; ++nt) acc[nt] = (f32x4){0.f, 0.f, 0.f, 0.f};

    #pragma unroll 4
    for (int kb = 0; kb < 16; ++kb) {
        float4 a0 = Xf4[row * 128 + kb * 8 + q * 2];
        float4 a1 = Xf4[row * 128 + kb * 8 + q * 2 + 1];
        f16x8 af;
        af[0] = (_Float16)a0.x; af[1] = (_Float16)a0.y;
        af[2] = (_Float16)a0.z; af[3] = (_Float16)a0.w;
        af[4] = (_Float16)a1.x; af[5] = (_Float16)a1.y;
        af[6] = (_Float16)a1.z; af[7] = (_Float16)a1.w;
        #pragma unroll
        for (int nt = 0; nt < 4; ++nt) {
            int col = nb * 64 + nt * 16 + r16;
            UU4 tmp; tmp.s = WpU4[(kb * 512 + col) * 4 + q];
            acc[nt] = __builtin_amdgcn_mfma_f32_16x16x32_f16(
                af, __builtin_bit_cast(f16x8, tmp.v), acc[nt], 0, 0, 0);
        }
    }

    const int rbase = mb * 64 + wave * 16 + q * 4;
    #pragma unroll
    for (int nt = 0; nt < 4; ++nt) {
        int col = nb * 64 + nt * 16 + r16;
        float bv = bias[col];
        #pragma unroll
        for (int rr = 0; rr < 4; ++rr) {
            out[(size_t)(rbase + rr) * 512 + col] = acc[nt][rr] + bv;
        }
    }
}

// ---------------------------------------------------------------------------
// Kernel 2: recurrence, pure MFMA. One block per batch (32 blocks, 256 thr,
// 1 wave/SIMD). A-operand = h replicated across all 16 M-rows (uniform-per-
// quad LDS broadcast read, ~free) -> every acc row holds the matvec.
// B (W_hh): k=0..415 register-resident (64 uint4 pinned to AGPR = 256 regs,
// 40 uint4 pinned to VGPR = 160 regs), k=416..511 streamed from a static
// 96 KB LDS image (stride-1 ds_read_b128, conflict-free).
// 128 MFMA/wave/step ~= 621 cyc issue; one barrier/step; h double-buffered.
// ---------------------------------------------------------------------------
__global__ __launch_bounds__(256, 1) void rnn_rec(const uint4* __restrict__ Wp4,
                                                  float* __restrict__ out) {
    extern __shared__ char smem[];
    uint4*  LBS = (uint4*)smem;                 // 6144 uint4 = 96 KB (kb 13..15)
    __half* hb  = (__half*)(smem + 98304);      // 2 x 512 halves (double buffer)

    const int b    = blockIdx.x;
    const int t    = threadIdx.x;
    const int lane = t & 63;
    const int w    = t >> 6;       // wave: owns cols [w*128, w*128+128)
    const int q    = lane >> 4;    // quad 0..3
    const int r16  = lane & 15;

    // Stage streamed B-fragments (k-blocks 13..15) into LDS.
    // Read layout: LBS[(s*8 + nt)*256 + t] is wave w, lane `lane`'s fragment
    // for stream-block s, N-tile nt. Each thread stages its own 24 words.
    #pragma unroll
    for (int j = 0; j < 24; ++j) {
        int kb  = 13 + (j >> 3);
        int col = w * 128 + (j & 7) * 16 + r16;
        LBS[j * 256 + t] = Wp4[(kb * 512 + col) * 4 + q];
    }

    // Resident B-fragments: k-blocks 0..12 x 8 N-tiles = 104 uint4 / lane.
    u32x4 Bf[104];
    #pragma unroll
    for (int kb = 0; kb < 13; ++kb) {
        #pragma unroll
        for (int nt = 0; nt < 8; ++nt) {
            int col = w * 128 + nt * 16 + r16;
            UU4 tmp; tmp.s = Wp4[(kb * 512 + col) * 4 + q];
            Bf[kb * 8 + nt] = tmp.v;
        }
    }
    // Pin: first 64 fragments -> AGPRs (exactly 256), rest -> VGPRs (160).
    #pragma unroll
    for (int i = 0; i < 64; ++i) asm volatile("" : "+a"(Bf[i]));
    #pragma unroll
    for (int i = 64; i < 104; ++i) asm volatile("" : "+v"(Bf[i]));

    float* orow = out + (size_t)b * SEQ * DIM;
    const int c0 = w * 128 + (2 * q) * 16 + r16;   // this thread's 2 output cols
    const int c1 = c0 + 16;

    // Step 0: h = tanh(xw).
    float xw0 = orow[c0], xw1 = orow[c1];
    float h0 = tanh_fast(xw0), h1 = tanh_fast(xw1);
    orow[c0] = h0; orow[c1] = h1;
    hb[c0] = __float2half(h0); hb[c1] = __float2half(h1);
    xw0 = orow[DIM + c0]; xw1 = orow[DIM + c1];    // prefetch step 1's xw
    __syncthreads();

    #pragma unroll 1
    for (int step = 1; step < SEQ; ++step) {
        orow += DIM;
        const __half* ha = hb + (((step & 1) ^ 1) << 9);   // h_{t-1}

        f32x4 m[8];
        #pragma unroll
        for (int i = 0; i < 8; ++i) m[i] = (f32x4){0.f, 0.f, 0.f, 0.f};

        // Streamed k-blocks first (LDS reads fill the pipe while MFMAs start).
        #pragma unroll
        for (int s = 0; s < 3; ++s) {
            f16x8 af = *(const f16x8*)(ha + (13 + s) * 32 + q * 8);
            #pragma unroll
            for (int nt = 0; nt < 8; ++nt) {
                UU4 tmp; tmp.s = LBS[(s * 8 + nt) * 256 + t];
                m[nt] = __builtin_amdgcn_mfma_f32_16x16x32_f16(
                    af, __builtin_bit_cast(f16x8, tmp.v), m[nt], 0, 0, 0);
            }
        }
        // Resident k-blocks.
        #pragma unroll
        for (int kb = 0; kb < 13; ++kb) {
            f16x8 af = *(const f16x8*)(ha + kb * 32 + q * 8);
            #pragma unroll
            for (int nt = 0; nt < 8; ++nt) {
                m[nt] = __builtin_amdgcn_mfma_f32_16x16x32_f16(
                    af, __builtin_bit_cast(f16x8, Bf[kb * 8 + nt]), m[nt], 0, 0, 0);
            }
        }

        // All acc rows are equal (replicated A): reg 0 of tiles 2q, 2q+1
        // hold cols c0, c1 for this lane.
        float p0 = (q == 0 ? m[0][0] : q == 1 ? m[2][0] : q == 2 ? m[4][0] : m[6][0]) + xw0;
        float p1 = (q == 0 ? m[1][0] : q == 1 ? m[3][0] : q == 2 ? m[5][0] : m[7][0]) + xw1;
        h0 = tanh_fast(p0);
        h1 = tanh_fast(p1);

        orow[c0] = h0; orow[c1] = h1;
        __half* hw = hb + ((step & 1) << 9);
        hw[c0] = __float2half(h0); hw[c1] = __float2half(h1);
        // Prefetch next xw (step 1023 reads into the h_final region: in-bounds,
        // value unused).
        xw0 = orow[DIM + c0]; xw1 = orow[DIM + c1];
        __syncthreads();
    }

    float* hf = out + (size_t)BATCH * SEQ * DIM + (size_t)b * DIM;
    hf[c0] = h0; hf[c1] = h1;
}

extern "C" void kernel_launch(void* const* d_in, const int* in_sizes, int n_in,
                              void* d_out, int out_size, void* d_ws, size_t ws_size,
                              hipStream_t stream) {
    const float* X    = (const float*)d_in[0];   // [32,1024,512] fp32
    const float* Wxh  = (const float*)d_in[1];   // [512,512] fp32
    const float* Whh  = (const float*)d_in[2];   // [512,512] fp32
    const float* bias = (const float*)d_in[3];   // [512] fp32
    float* out = (float*)d_out;

    __half* WpXh = (__half*)d_ws;                          // 512 KB @ 0
    __half* WpHh = (__half*)((char*)d_ws + (512u << 10));  // 512 KB @ 512K

    (void)hipFuncSetAttribute((const void*)rnn_rec,
                              hipFuncAttributeMaxDynamicSharedMemorySize, 100352);

    pack_w<<<512, 512, 0, stream>>>(Wxh, WpXh);
    pack_w<<<512, 512, 0, stream>>>(Whh, WpHh);
    gemm_xw<<<dim3(8, 512), 256, 0, stream>>>(X, WpXh, bias, out);
    rnn_rec<<<BATCH, 256, 100352, stream>>>((const uint4*)WpHh, out);
}